// Round 8
// baseline (193.077 us; speedup 1.0000x reference)
//
#include <hip/hip_runtime.h>
#include <hip/hip_bf16.h>

// SE3StructEncoder: sparse edge-MLP graph network. B=2, L=512, H=128, 3 layers.
// Round 8: edge kernel was ~97% latency-stalled (3 barrier-separated serial
// stages x 2 chunks). ET 32->64 (one round for ~97% of rows, mean cnt=51),
// j/dist computed inline in fill role (staging stage+barrier removed),
// prep+build merged into one launch. Node/input MFMA kernels unchanged.

#define Hc 128
#define Lc 512
#define ROWS 1024     // B*L

typedef __bf16 bf16x8 __attribute__((ext_vector_type(8)));
typedef float  f32x4  __attribute__((ext_vector_type(4)));

__device__ __forceinline__ float silu(float x) {
    return x / (1.f + __expf(-x));
}

// ---- merged one-time prep: edge lists (blocks 0..255) + bf16 weight
// transposes (blocks 256..1423) ----
// in_wt[col][k](128x32)   = in_w[k][col]
// w1et[l][col][k](256x128)= col<128 ? e_w1[l][k][col] : e_w1[l][128+k][col-128]
// w2te[l][col][k](128x128)= e_w2[l][k][col]
// w1nt[l][col][k](128x256)= n_w1[l][k][col]
// w2nt[l][col][k](128x128)= n_w2[l][k][col]
__global__ __launch_bounds__(256) void prep_all(
    const float* __restrict__ contacts,
    unsigned short* __restrict__ elist, int* __restrict__ ecnt,
    const float* __restrict__ in_w, const float* __restrict__ e_w1,
    const float* __restrict__ e_w2, const float* __restrict__ n_w1,
    const float* __restrict__ n_w2,
    __bf16* __restrict__ in_wt, __bf16* __restrict__ w1et,
    __bf16* __restrict__ w2te, __bf16* __restrict__ w1nt,
    __bf16* __restrict__ w2nt) {
    int blk = blockIdx.x;
    if (blk < 256) {
        // edge-list build: 4 rows per block, one wave per row
        int r = blk * 4 + (threadIdx.x >> 6);
        int lane = threadIdx.x & 63;
        const float* row = contacts + (size_t)r * Lc;
        int cnt = 0;
        for (int base = 0; base < Lc; base += 64) {
            float v = row[base + lane];
            unsigned long long mask = __ballot(v > 0.f);
            if (v > 0.f) {
                int pos = cnt + __popcll(mask & ((1ull << lane) - 1ull));
                elist[r * Lc + pos] = (unsigned short)(base + lane);
            }
            cnt += __popcll(mask);
        }
        if (lane == 0) ecnt[r] = cnt;
        return;
    }
    int idx = (blk - 256) * 256 + threadIdx.x;   // 1168*256 = 299008 exactly
    if (idx < 4096) {
        int col = idx >> 5, k = idx & 31;
        in_wt[idx] = (__bf16)in_w[k * Hc + col];
    } else if (idx < 4096 + 98304) {
        int q = idx - 4096;
        int l = q / 32768, r = q % 32768;
        int col = r >> 7, k = r & 127;
        float v = (col < 128) ? e_w1[(size_t)l * 258 * Hc + k * Hc + col]
                              : e_w1[(size_t)l * 258 * Hc + (128 + k) * Hc + (col - 128)];
        w1et[q] = (__bf16)v;
    } else if (idx < 4096 + 98304 + 49152) {
        int q = idx - 4096 - 98304;
        int l = q / 16384, r = q % 16384;
        int col = r >> 7, k = r & 127;
        w2te[q] = (__bf16)e_w2[(size_t)l * 16384 + k * Hc + col];
    } else if (idx < 4096 + 98304 + 49152 + 98304) {
        int q = idx - 4096 - 98304 - 49152;
        int l = q / 32768, r = q % 32768;
        int col = r >> 8, k = r & 255;
        w1nt[q] = (__bf16)n_w1[(size_t)l * 32768 + k * Hc + col];
    } else {
        int q = idx - 4096 - 98304 - 49152 - 98304;
        int l = q / 16384, r = q % 16384;
        int col = r >> 7, k = r & 127;
        w2nt[q] = (__bf16)n_w2[(size_t)l * 16384 + k * Hc + col];
    }
}

// ------- input proj + layer-0 hi/hj via MFMA: 16 rows/block, 64 blocks -------
__global__ __launch_bounds__(256) void input_mfma(
    const float* __restrict__ nf, const __bf16* __restrict__ in_wt,
    const float* __restrict__ in_b,
    const __bf16* __restrict__ w1et0, const float* __restrict__ b1e,
    const float* __restrict__ fold,
    float* __restrict__ h, float* __restrict__ hi, float* __restrict__ hj) {
    int r0 = blockIdx.x * 16;
    int t = threadIdx.x;
    int l = t & 63, w = t >> 6;
    int lr = l & 15, g = l >> 4;
    __shared__ __bf16 A0[16 * 32];     // swizzled [row][k], blk ^ (row&3)
    __shared__ __bf16 A3[16 * Hc];     // swizzled [row][k], blk ^ (row&7)

    if (t < 64) {
        int row = t >> 2, blk = t & 3, k0 = blk * 8;
        const float* src = &nf[(size_t)(r0 + row) * 32 + k0];
        float4 v0 = *(const float4*)src, v1 = *(const float4*)(src + 4);
        bf16x8 o;
        o[0] = (__bf16)v0.x; o[1] = (__bf16)v0.y; o[2] = (__bf16)v0.z; o[3] = (__bf16)v0.w;
        o[4] = (__bf16)v1.x; o[5] = (__bf16)v1.y; o[6] = (__bf16)v1.z; o[7] = (__bf16)v1.w;
        *(bf16x8*)&A0[row * 32 + (blk ^ (row & 3)) * 8] = o;
    }
    int c0 = w * 32;
    bf16x8 bf0[2];
#pragma unroll
    for (int nt = 0; nt < 2; nt++)
        bf0[nt] = *(const bf16x8*)&in_wt[(size_t)(c0 + nt * 16 + lr) * 32 + g * 8];
    __syncthreads();
    f32x4 acc[2] = {};
    {
        bf16x8 a = *(const bf16x8*)&A0[lr * 32 + (g ^ (lr & 3)) * 8];
        acc[0] = __builtin_amdgcn_mfma_f32_16x16x32_bf16(a, bf0[0], acc[0], 0, 0, 0);
        acc[1] = __builtin_amdgcn_mfma_f32_16x16x32_bf16(a, bf0[1], acc[1], 0, 0, 0);
    }
#pragma unroll
    for (int nt = 0; nt < 2; nt++) {
        int col = c0 + nt * 16 + lr;
        float bb = in_b[col];
#pragma unroll
        for (int j = 0; j < 4; j++) {
            int row = g * 4 + j;
            float hv = acc[nt][j] + bb;
            h[(size_t)(r0 + row) * Hc + col] = hv;
            A3[row * Hc + ((col >> 3) ^ (row & 7)) * 8 + (col & 7)] = (__bf16)hv;
        }
    }
    __syncthreads();
    int c3 = w * 64;
    bf16x8 b3[4][4];
#pragma unroll
    for (int nt = 0; nt < 4; nt++)
#pragma unroll
        for (int ks = 0; ks < 4; ks++)
            b3[nt][ks] = *(const bf16x8*)&w1et0[
                (size_t)(c3 + nt * 16 + lr) * Hc + ks * 32 + g * 8];
    f32x4 acc3[4] = {};
#pragma unroll
    for (int ks = 0; ks < 4; ks++) {
        bf16x8 a = *(const bf16x8*)&A3[lr * Hc + (((ks * 4 + g) ^ (lr & 7))) * 8];
#pragma unroll
        for (int nt = 0; nt < 4; nt++)
            acc3[nt] = __builtin_amdgcn_mfma_f32_16x16x32_bf16(a, b3[nt][ks], acc3[nt], 0, 0, 0);
    }
#pragma unroll
    for (int nt = 0; nt < 4; nt++) {
        int col = c3 + nt * 16 + lr;
#pragma unroll
        for (int j = 0; j < 4; j++) {
            int row = g * 4 + j;
            if (col < 128)
                hi[(size_t)(r0 + row) * Hc + col] = acc3[nt][j] + b1e[col] + fold[col];
            else
                hj[(size_t)(r0 + row) * Hc + (col - 128)] = acc3[nt][j];
        }
    }
}

// ---------------- edge kernel: per (b,i) row, ET=64, inline j/dist ----------------
// m_i = sum_{j in edges(i)} silu( silu(pre_ij) @ w2 + b2 )
// pre_ij = hi'[i] + hj[j] + dist(i,j)*w1d   (b1 + contact*w1c folded into hi')
// Fill: thread t -> edge e=t>>2 (0..63), 32-col slice cq=t&3. S[64][128] bf16,
// 16B blocks XOR-swizzled by (e&7) -- same involution as validated round-5 kernel.
__global__ __launch_bounds__(256) void edge_kernel(
    const float* __restrict__ hi, const float* __restrict__ hj,
    const float* __restrict__ coords,
    const unsigned short* __restrict__ elist, const int* __restrict__ ecnt,
    const float* __restrict__ w1d, const __bf16* __restrict__ w2t,
    const float* __restrict__ b2, float* __restrict__ m_out) {
    int r = blockIdx.x;
    int b = r >> 9;
    int i = r & (Lc - 1);
    int t = threadIdx.x;
    int l = t & 63, w = t >> 6;
    int lr = l & 15, g = l >> 4;

    __shared__ __bf16 S[64 * Hc];    // 16 KB, swizzled [edge][c]

    int cnt = ecnt[r];

    // B fragments: wave w owns output cols w*32..w*32+31
    bf16x8 bf[2][4];
#pragma unroll
    for (int nt = 0; nt < 2; nt++)
#pragma unroll
        for (int kk = 0; kk < 4; kk++)
            bf[nt][kk] = *(const bf16x8*)&w2t[
                (size_t)(w * 32 + nt * 16 + lr) * Hc + kk * 32 + g * 8];
    float b2v[2] = { b2[w * 32 + lr], b2[w * 32 + 16 + lr] };
    float msum[2] = { 0.f, 0.f };

    // fill-role constants
    int e_f = t >> 2;               // edge slot 0..63
    int cq  = t & 3;
    int c0  = cq * 32;
    float cx = coords[(b * Lc + i) * 3 + 0];
    float cy = coords[(b * Lc + i) * 3 + 1];
    float cz = coords[(b * Lc + i) * 3 + 2];
    const float* hjb   = hj + (size_t)(b * Lc) * Hc;
    const float* hirow = hi + (size_t)r * Hc + c0;
    const float* wdrow = w1d + c0;

    for (int base = 0; base < cnt; base += 64) {
        if (base) __syncthreads();
        // ---- fill S: j/dist inline (4 threads/edge duplicate the cheap part) ----
        if (base + e_f < cnt) {
            int j = elist[r * Lc + base + e_f];
            float dx = cx - coords[(b * Lc + j) * 3 + 0];
            float dy = cy - coords[(b * Lc + j) * 3 + 1];
            float dz = cz - coords[(b * Lc + j) * 3 + 2];
            float d = sqrtf(dx * dx + dy * dy + dz * dz);
            const float* hjrow = hjb + (size_t)j * Hc + c0;
#pragma unroll
            for (int p = 0; p < 4; p++) {
                float4 ha = *(const float4*)&hjrow[p * 8];
                float4 hb = *(const float4*)&hjrow[p * 8 + 4];
                float4 ia = *(const float4*)&hirow[p * 8];
                float4 ib = *(const float4*)&hirow[p * 8 + 4];
                float4 wa = *(const float4*)&wdrow[p * 8];
                float4 wb = *(const float4*)&wdrow[p * 8 + 4];
                bf16x8 o;
                o[0] = (__bf16)silu(ia.x + ha.x + d * wa.x);
                o[1] = (__bf16)silu(ia.y + ha.y + d * wa.y);
                o[2] = (__bf16)silu(ia.z + ha.z + d * wa.z);
                o[3] = (__bf16)silu(ia.w + ha.w + d * wa.w);
                o[4] = (__bf16)silu(ib.x + hb.x + d * wb.x);
                o[5] = (__bf16)silu(ib.y + hb.y + d * wb.y);
                o[6] = (__bf16)silu(ib.z + hb.z + d * wb.z);
                o[7] = (__bf16)silu(ib.w + hb.w + d * wb.w);
                *(bf16x8*)&S[e_f * Hc + ((cq * 4 + p) ^ (e_f & 7)) * 8] = o;
            }
        } else {
            bf16x8 z = {};
#pragma unroll
            for (int p = 0; p < 4; p++)
                *(bf16x8*)&S[e_f * Hc + ((cq * 4 + p) ^ (e_f & 7)) * 8] = z;
        }
        __syncthreads();

        // ---- MFMA: D[e][col] = S @ w2, 4 M-tiles x 2 N-tiles x 4 K-steps ----
        f32x4 acc[4][2] = {};
#pragma unroll
        for (int ks = 0; ks < 4; ks++) {
            bf16x8 a[4];
#pragma unroll
            for (int mt = 0; mt < 4; mt++)
                a[mt] = *(const bf16x8*)&S[(mt * 16 + lr) * Hc + ((ks * 4 + g) ^ (lr & 7)) * 8];
#pragma unroll
            for (int mt = 0; mt < 4; mt++) {
                acc[mt][0] = __builtin_amdgcn_mfma_f32_16x16x32_bf16(a[mt], bf[0][ks], acc[mt][0], 0, 0, 0);
                acc[mt][1] = __builtin_amdgcn_mfma_f32_16x16x32_bf16(a[mt], bf[1][ks], acc[mt][1], 0, 0, 0);
            }
        }

        // ---- second silu + predicated colsum (D row = mt*16 + 4g + jj) ----
#pragma unroll
        for (int mt = 0; mt < 4; mt++)
#pragma unroll
            for (int nt = 0; nt < 2; nt++)
#pragma unroll
                for (int jj = 0; jj < 4; jj++) {
                    if (base + mt * 16 + g * 4 + jj < cnt)
                        msum[nt] += silu(acc[mt][nt][jj] + b2v[nt]);
                }
    }

    // cross-lane colsum: lanes l, l^16, l^32 share col (l&15)
    float v0 = msum[0]; v0 += __shfl_xor(v0, 16); v0 += __shfl_xor(v0, 32);
    float v1 = msum[1]; v1 += __shfl_xor(v1, 16); v1 += __shfl_xor(v1, 32);
    if (l < 16) {
        m_out[(size_t)r * Hc + w * 32 + l]      = v0;
        m_out[(size_t)r * Hc + w * 32 + 16 + l] = v1;
    }
}

// ------- node update + next-layer hi/hj via MFMA: 16 rows/block, 64 blocks -------
__global__ __launch_bounds__(256) void node_mfma(
    const float* __restrict__ h, const float* __restrict__ m,
    const __bf16* __restrict__ w1nt, const float* __restrict__ b1n,
    const __bf16* __restrict__ w2nt, const float* __restrict__ b2n,
    float* __restrict__ hout, int do_hij,
    const __bf16* __restrict__ w1et, const float* __restrict__ b1e,
    const float* __restrict__ fold,
    float* __restrict__ hi, float* __restrict__ hj) {
    int r0 = blockIdx.x * 16;
    int t = threadIdx.x;
    int l = t & 63, w = t >> 6;
    int lr = l & 15, g = l >> 4;
    __shared__ __bf16 A1[16 * 256];
    __shared__ __bf16 A2[16 * Hc];
    __shared__ __bf16 A3[16 * Hc];
    __shared__ float hbuf[16 * Hc];

#pragma unroll
    for (int it = 0; it < 2; it++) {
        int idx = t + it * 256;
        int row = idx >> 5, blk = idx & 31, k0 = blk * 8;
        const float* src = (k0 < 128)
            ? &h[(size_t)(r0 + row) * Hc + k0]
            : &m[(size_t)(r0 + row) * Hc + (k0 - 128)];
        float4 v0 = *(const float4*)src, v1 = *(const float4*)(src + 4);
        bf16x8 o;
        o[0] = (__bf16)v0.x; o[1] = (__bf16)v0.y; o[2] = (__bf16)v0.z; o[3] = (__bf16)v0.w;
        o[4] = (__bf16)v1.x; o[5] = (__bf16)v1.y; o[6] = (__bf16)v1.z; o[7] = (__bf16)v1.w;
        *(bf16x8*)&A1[row * 256 + (blk ^ (row & 7)) * 8] = o;
        if (k0 < 128) {
            *(float4*)&hbuf[row * Hc + k0] = v0;
            *(float4*)&hbuf[row * Hc + k0 + 4] = v1;
        }
    }
    int c0 = w * 32;
    bf16x8 b1f[2][8];
#pragma unroll
    for (int nt = 0; nt < 2; nt++)
#pragma unroll
        for (int ks = 0; ks < 8; ks++)
            b1f[nt][ks] = *(const bf16x8*)&w1nt[
                (size_t)(c0 + nt * 16 + lr) * 256 + ks * 32 + g * 8];
    __syncthreads();

    f32x4 acc[2] = {};
#pragma unroll
    for (int ks = 0; ks < 8; ks++) {
        bf16x8 a = *(const bf16x8*)&A1[lr * 256 + (((ks * 4 + g) ^ (lr & 7))) * 8];
        acc[0] = __builtin_amdgcn_mfma_f32_16x16x32_bf16(a, b1f[0][ks], acc[0], 0, 0, 0);
        acc[1] = __builtin_amdgcn_mfma_f32_16x16x32_bf16(a, b1f[1][ks], acc[1], 0, 0, 0);
    }
#pragma unroll
    for (int nt = 0; nt < 2; nt++) {
        int col = c0 + nt * 16 + lr;
        float bb = b1n[col];
#pragma unroll
        for (int j = 0; j < 4; j++) {
            int row = g * 4 + j;
            A2[row * Hc + ((col >> 3) ^ (row & 7)) * 8 + (col & 7)] =
                (__bf16)silu(acc[nt][j] + bb);
        }
    }
    __syncthreads();

    bf16x8 b2f[2][4];
#pragma unroll
    for (int nt = 0; nt < 2; nt++)
#pragma unroll
        for (int ks = 0; ks < 4; ks++)
            b2f[nt][ks] = *(const bf16x8*)&w2nt[
                (size_t)(c0 + nt * 16 + lr) * Hc + ks * 32 + g * 8];
    f32x4 acc2[2] = {};
#pragma unroll
    for (int ks = 0; ks < 4; ks++) {
        bf16x8 a = *(const bf16x8*)&A2[lr * Hc + (((ks * 4 + g) ^ (lr & 7))) * 8];
        acc2[0] = __builtin_amdgcn_mfma_f32_16x16x32_bf16(a, b2f[0][ks], acc2[0], 0, 0, 0);
        acc2[1] = __builtin_amdgcn_mfma_f32_16x16x32_bf16(a, b2f[1][ks], acc2[1], 0, 0, 0);
    }
#pragma unroll
    for (int nt = 0; nt < 2; nt++) {
        int col = c0 + nt * 16 + lr;
        float bb = b2n[col];
#pragma unroll
        for (int j = 0; j < 4; j++) {
            int row = g * 4 + j;
            float hnew = hbuf[row * Hc + col] + acc2[nt][j] + bb;
            hout[(size_t)(r0 + row) * Hc + col] = hnew;
            A3[row * Hc + ((col >> 3) ^ (row & 7)) * 8 + (col & 7)] = (__bf16)hnew;
        }
    }
    if (!do_hij) return;
    __syncthreads();

    int c3 = w * 64;
    bf16x8 b3[4][4];
#pragma unroll
    for (int nt = 0; nt < 4; nt++)
#pragma unroll
        for (int ks = 0; ks < 4; ks++)
            b3[nt][ks] = *(const bf16x8*)&w1et[
                (size_t)(c3 + nt * 16 + lr) * Hc + ks * 32 + g * 8];
    f32x4 acc3[4] = {};
#pragma unroll
    for (int ks = 0; ks < 4; ks++) {
        bf16x8 a = *(const bf16x8*)&A3[lr * Hc + (((ks * 4 + g) ^ (lr & 7))) * 8];
#pragma unroll
        for (int nt = 0; nt < 4; nt++)
            acc3[nt] = __builtin_amdgcn_mfma_f32_16x16x32_bf16(a, b3[nt][ks], acc3[nt], 0, 0, 0);
    }
#pragma unroll
    for (int nt = 0; nt < 4; nt++) {
        int col = c3 + nt * 16 + lr;
#pragma unroll
        for (int j = 0; j < 4; j++) {
            int row = g * 4 + j;
            if (col < 128)
                hi[(size_t)(r0 + row) * Hc + col] = acc3[nt][j] + b1e[col] + fold[col];
            else
                hj[(size_t)(r0 + row) * Hc + (col - 128)] = acc3[nt][j];
        }
    }
}

extern "C" void kernel_launch(void* const* d_in, const int* in_sizes, int n_in,
                              void* d_out, int out_size, void* d_ws, size_t ws_size,
                              hipStream_t stream) {
    const float* coords     = (const float*)d_in[0];
    const float* contacts   = (const float*)d_in[1];
    const float* node_feats = (const float*)d_in[2];
    const float* in_w       = (const float*)d_in[3];
    const float* in_b       = (const float*)d_in[4];
    const float* e_w1       = (const float*)d_in[5];   // 3 x 258 x 128
    const float* e_b1       = (const float*)d_in[6];
    const float* e_w2       = (const float*)d_in[7];   // 3 x 128 x 128
    const float* e_b2       = (const float*)d_in[8];
    const float* n_w1       = (const float*)d_in[9];   // 3 x 256 x 128
    const float* n_b1       = (const float*)d_in[10];
    const float* n_w2       = (const float*)d_in[11];  // 3 x 128 x 128
    const float* n_b2       = (const float*)d_in[12];

    float* ws = (float*)d_ws;
    float* h  = ws;                                    // 131072 floats
    float* hi = ws + 131072;
    float* hj = ws + 262144;
    float* m  = ws + 393216;
    unsigned short* elist = (unsigned short*)(ws + 524288);   // 262144 floats
    int*   ecnt = (int*)(ws + 786432);                        // 1024
    __bf16* in_wt = (__bf16*)(ws + 787456);                   // 4096 bf16
    __bf16* w1et  = (__bf16*)(ws + 789504);                   // 98304 bf16
    __bf16* w2te  = (__bf16*)(ws + 838656);                   // 49152 bf16
    __bf16* w1nt  = (__bf16*)(ws + 863232);                   // 98304 bf16
    __bf16* w2nt  = (__bf16*)(ws + 912384);                   // 49152 bf16

    prep_all<<<256 + 1168, 256, 0, stream>>>(
        contacts, elist, ecnt,
        in_w, e_w1, e_w2, n_w1, n_w2,
        in_wt, w1et, w2te, w1nt, w2nt);
    input_mfma<<<ROWS / 16, 256, 0, stream>>>(
        node_feats, in_wt, in_b,
        w1et, e_b1, e_w1 + (size_t)257 * Hc,
        h, hi, hj);

    for (int l = 0; l < 3; l++) {
        const float* w1 = e_w1 + (size_t)l * 258 * Hc;
        edge_kernel<<<ROWS, 256, 0, stream>>>(hi, hj, coords, elist, ecnt,
                                              w1 + 2 * Hc * Hc,
                                              w2te + (size_t)l * Hc * Hc,
                                              e_b2 + l * Hc, m);
        int do_hij = (l < 2);
        int lnext = (l + 1 < 3) ? l + 1 : 0;
        float* hout = (l == 2) ? (float*)d_out : h;
        node_mfma<<<ROWS / 16, 256, 0, stream>>>(
            h, m,
            w1nt + (size_t)l * 128 * 256, n_b1 + l * Hc,
            w2nt + (size_t)l * 128 * 128, n_b2 + l * Hc,
            hout, do_hij,
            w1et + (size_t)lnext * 256 * 128, e_b1 + lnext * Hc,
            e_w1 + (size_t)lnext * 258 * Hc + (size_t)257 * Hc,
            hi, hj);
    }
}

// Round 10
// 184.608 us; speedup vs baseline: 1.0459x; 1.0459x over previous
//
#include <hip/hip_runtime.h>
#include <hip/hip_bf16.h>

// SE3StructEncoder: sparse edge-MLP graph network. B=2, L=512, H=128, 3 layers.
// Round 10: fix round-9 correctness bug (cnt>64 rows dropped edges: cnt is
// Binomial(512,0.1), ~3% of rows exceed 64). Each half-block now strided-loops
// its windows [h*32+64k, +32). Split 2 blocks/row (grid 2048) retained for
// 2x co-residency on the latency-bound edge phase. Node/input/prep unchanged.

#define Hc 128
#define Lc 512
#define ROWS 1024     // B*L

typedef __bf16 bf16x8 __attribute__((ext_vector_type(8)));
typedef float  f32x4  __attribute__((ext_vector_type(4)));

__device__ __forceinline__ float silu(float x) {
    return x / (1.f + __expf(-x));
}

// ---- merged one-time prep: edge lists (blocks 0..255) + bf16 weight
// transposes (blocks 256..1423) ----
__global__ __launch_bounds__(256) void prep_all(
    const float* __restrict__ contacts,
    unsigned short* __restrict__ elist, int* __restrict__ ecnt,
    const float* __restrict__ in_w, const float* __restrict__ e_w1,
    const float* __restrict__ e_w2, const float* __restrict__ n_w1,
    const float* __restrict__ n_w2,
    __bf16* __restrict__ in_wt, __bf16* __restrict__ w1et,
    __bf16* __restrict__ w2te, __bf16* __restrict__ w1nt,
    __bf16* __restrict__ w2nt) {
    int blk = blockIdx.x;
    if (blk < 256) {
        int r = blk * 4 + (threadIdx.x >> 6);
        int lane = threadIdx.x & 63;
        const float* row = contacts + (size_t)r * Lc;
        int cnt = 0;
        for (int base = 0; base < Lc; base += 64) {
            float v = row[base + lane];
            unsigned long long mask = __ballot(v > 0.f);
            if (v > 0.f) {
                int pos = cnt + __popcll(mask & ((1ull << lane) - 1ull));
                elist[r * Lc + pos] = (unsigned short)(base + lane);
            }
            cnt += __popcll(mask);
        }
        if (lane == 0) ecnt[r] = cnt;
        return;
    }
    int idx = (blk - 256) * 256 + threadIdx.x;   // 1168*256 = 299008 exactly
    if (idx < 4096) {
        int col = idx >> 5, k = idx & 31;
        in_wt[idx] = (__bf16)in_w[k * Hc + col];
    } else if (idx < 4096 + 98304) {
        int q = idx - 4096;
        int l = q / 32768, r = q % 32768;
        int col = r >> 7, k = r & 127;
        float v = (col < 128) ? e_w1[(size_t)l * 258 * Hc + k * Hc + col]
                              : e_w1[(size_t)l * 258 * Hc + (128 + k) * Hc + (col - 128)];
        w1et[q] = (__bf16)v;
    } else if (idx < 4096 + 98304 + 49152) {
        int q = idx - 4096 - 98304;
        int l = q / 16384, r = q % 16384;
        int col = r >> 7, k = r & 127;
        w2te[q] = (__bf16)e_w2[(size_t)l * 16384 + k * Hc + col];
    } else if (idx < 4096 + 98304 + 49152 + 98304) {
        int q = idx - 4096 - 98304 - 49152;
        int l = q / 32768, r = q % 32768;
        int col = r >> 8, k = r & 255;
        w1nt[q] = (__bf16)n_w1[(size_t)l * 32768 + k * Hc + col];
    } else {
        int q = idx - 4096 - 98304 - 49152 - 98304;
        int l = q / 16384, r = q % 16384;
        int col = r >> 7, k = r & 127;
        w2nt[q] = (__bf16)n_w2[(size_t)l * 16384 + k * Hc + col];
    }
}

// ------- input proj + layer-0 hi/hj via MFMA: 16 rows/block, 64 blocks -------
__global__ __launch_bounds__(256) void input_mfma(
    const float* __restrict__ nf, const __bf16* __restrict__ in_wt,
    const float* __restrict__ in_b,
    const __bf16* __restrict__ w1et0, const float* __restrict__ b1e,
    const float* __restrict__ fold,
    float* __restrict__ h, float* __restrict__ hi, float* __restrict__ hj) {
    int r0 = blockIdx.x * 16;
    int t = threadIdx.x;
    int l = t & 63, w = t >> 6;
    int lr = l & 15, g = l >> 4;
    __shared__ __bf16 A0[16 * 32];
    __shared__ __bf16 A3[16 * Hc];

    if (t < 64) {
        int row = t >> 2, blk = t & 3, k0 = blk * 8;
        const float* src = &nf[(size_t)(r0 + row) * 32 + k0];
        float4 v0 = *(const float4*)src, v1 = *(const float4*)(src + 4);
        bf16x8 o;
        o[0] = (__bf16)v0.x; o[1] = (__bf16)v0.y; o[2] = (__bf16)v0.z; o[3] = (__bf16)v0.w;
        o[4] = (__bf16)v1.x; o[5] = (__bf16)v1.y; o[6] = (__bf16)v1.z; o[7] = (__bf16)v1.w;
        *(bf16x8*)&A0[row * 32 + (blk ^ (row & 3)) * 8] = o;
    }
    int c0 = w * 32;
    bf16x8 bf0[2];
#pragma unroll
    for (int nt = 0; nt < 2; nt++)
        bf0[nt] = *(const bf16x8*)&in_wt[(size_t)(c0 + nt * 16 + lr) * 32 + g * 8];
    __syncthreads();
    f32x4 acc[2] = {};
    {
        bf16x8 a = *(const bf16x8*)&A0[lr * 32 + (g ^ (lr & 3)) * 8];
        acc[0] = __builtin_amdgcn_mfma_f32_16x16x32_bf16(a, bf0[0], acc[0], 0, 0, 0);
        acc[1] = __builtin_amdgcn_mfma_f32_16x16x32_bf16(a, bf0[1], acc[1], 0, 0, 0);
    }
#pragma unroll
    for (int nt = 0; nt < 2; nt++) {
        int col = c0 + nt * 16 + lr;
        float bb = in_b[col];
#pragma unroll
        for (int j = 0; j < 4; j++) {
            int row = g * 4 + j;
            float hv = acc[nt][j] + bb;
            h[(size_t)(r0 + row) * Hc + col] = hv;
            A3[row * Hc + ((col >> 3) ^ (row & 7)) * 8 + (col & 7)] = (__bf16)hv;
        }
    }
    __syncthreads();
    int c3 = w * 64;
    bf16x8 b3[4][4];
#pragma unroll
    for (int nt = 0; nt < 4; nt++)
#pragma unroll
        for (int ks = 0; ks < 4; ks++)
            b3[nt][ks] = *(const bf16x8*)&w1et0[
                (size_t)(c3 + nt * 16 + lr) * Hc + ks * 32 + g * 8];
    f32x4 acc3[4] = {};
#pragma unroll
    for (int ks = 0; ks < 4; ks++) {
        bf16x8 a = *(const bf16x8*)&A3[lr * Hc + (((ks * 4 + g) ^ (lr & 7))) * 8];
#pragma unroll
        for (int nt = 0; nt < 4; nt++)
            acc3[nt] = __builtin_amdgcn_mfma_f32_16x16x32_bf16(a, b3[nt][ks], acc3[nt], 0, 0, 0);
    }
#pragma unroll
    for (int nt = 0; nt < 4; nt++) {
        int col = c3 + nt * 16 + lr;
#pragma unroll
        for (int j = 0; j < 4; j++) {
            int row = g * 4 + j;
            if (col < 128)
                hi[(size_t)(r0 + row) * Hc + col] = acc3[nt][j] + b1e[col] + fold[col];
            else
                hj[(size_t)(r0 + row) * Hc + (col - 128)] = acc3[nt][j];
        }
    }
}

// -------- edge kernel: 2 blocks per row (grid 2048), strided 32-edge windows --------
// half h processes windows [h*32 + 64k, +32) for k=0,1,...  -> covers any cnt.
// m_part[half][r] = partial colsum; summed in node_mfma staging.
// Fill: thread -> edge e_f=t>>3, 16-col slice cg=t&7; dist inline.
// S[32][128] bf16, 16B blocks XOR-swizzled by (e&7) (round-5 validated).
__global__ __launch_bounds__(256) void edge_kernel(
    const float* __restrict__ hi, const float* __restrict__ hj,
    const float* __restrict__ coords,
    const unsigned short* __restrict__ elist, const int* __restrict__ ecnt,
    const float* __restrict__ w1d, const __bf16* __restrict__ w2t,
    const float* __restrict__ b2, float* __restrict__ m_part) {
    int r = blockIdx.x >> 1, half = blockIdx.x & 1;
    int b = r >> 9;
    int i = r & (Lc - 1);
    int t = threadIdx.x;
    int l = t & 63, w = t >> 6;
    int lr = l & 15, g = l >> 4;

    __shared__ __bf16 S[32 * Hc];    // 8 KB, swizzled [edge][c]

    float* mp = m_part + ((size_t)half * ROWS + r) * Hc;
    int cnt = ecnt[r];

    // B fragments: wave w owns output cols w*32..w*32+31
    bf16x8 bf[2][4];
#pragma unroll
    for (int nt = 0; nt < 2; nt++)
#pragma unroll
        for (int kk = 0; kk < 4; kk++)
            bf[nt][kk] = *(const bf16x8*)&w2t[
                (size_t)(w * 32 + nt * 16 + lr) * Hc + kk * 32 + g * 8];
    float b2v[2] = { b2[w * 32 + lr], b2[w * 32 + 16 + lr] };
    float msum[2] = { 0.f, 0.f };

    // fill-role constants: thread -> (edge e_f, 16-col slice c0)
    int e_f = t >> 3;
    int cg  = t & 7;
    int c0  = cg * 16;
    float cxi = coords[(b * Lc + i) * 3 + 0];
    float cyi = coords[(b * Lc + i) * 3 + 1];
    float czi = coords[(b * Lc + i) * 3 + 2];
    float4 hi4[4], wd4[4];
#pragma unroll
    for (int q = 0; q < 4; q++) {
        hi4[q] = *(const float4*)&hi[(size_t)r * Hc + c0 + q * 4];
        wd4[q] = *(const float4*)&w1d[c0 + q * 4];
    }
    const float* hjb = hj + (size_t)(b * Lc) * Hc;

    int first = half * 32;
    for (int base = first; base < cnt; base += 64) {
        if (base != first) __syncthreads();
        int nloc = cnt - base; if (nloc > 32) nloc = 32;
        // ---- fill S ----
        bf16x8 o0, o1;
        if (e_f < nloc) {
            int j = elist[r * Lc + base + e_f];
            float dx = cxi - coords[(b * Lc + j) * 3 + 0];
            float dy = cyi - coords[(b * Lc + j) * 3 + 1];
            float dz = czi - coords[(b * Lc + j) * 3 + 2];
            float d = sqrtf(dx * dx + dy * dy + dz * dz);
            const float* hjrow = hjb + (size_t)j * Hc + c0;
            float v[16];
#pragma unroll
            for (int q = 0; q < 4; q++) {
                float4 hjv = *(const float4*)&hjrow[q * 4];
                v[q * 4 + 0] = silu(hi4[q].x + hjv.x + d * wd4[q].x);
                v[q * 4 + 1] = silu(hi4[q].y + hjv.y + d * wd4[q].y);
                v[q * 4 + 2] = silu(hi4[q].z + hjv.z + d * wd4[q].z);
                v[q * 4 + 3] = silu(hi4[q].w + hjv.w + d * wd4[q].w);
            }
#pragma unroll
            for (int u = 0; u < 8; u++) {
                o0[u] = (__bf16)v[u];
                o1[u] = (__bf16)v[8 + u];
            }
        } else {
#pragma unroll
            for (int u = 0; u < 8; u++) { o0[u] = (__bf16)0.f; o1[u] = (__bf16)0.f; }
        }
        int sw = e_f & 7;
        *(bf16x8*)&S[e_f * Hc + ((cg * 2) ^ sw) * 8]     = o0;
        *(bf16x8*)&S[e_f * Hc + ((cg * 2 + 1) ^ sw) * 8] = o1;
        __syncthreads();

        // ---- MFMA: D[e][col] = S @ w2, 2 M-tiles x 2 N-tiles x 4 K-steps ----
        f32x4 acc[2][2] = {};
#pragma unroll
        for (int ks = 0; ks < 4; ks++) {
            bf16x8 a0 = *(const bf16x8*)&S[lr * Hc + ((ks * 4 + g) ^ (lr & 7)) * 8];
            bf16x8 a1 = *(const bf16x8*)&S[(16 + lr) * Hc + ((ks * 4 + g) ^ (lr & 7)) * 8];
            acc[0][0] = __builtin_amdgcn_mfma_f32_16x16x32_bf16(a0, bf[0][ks], acc[0][0], 0, 0, 0);
            acc[0][1] = __builtin_amdgcn_mfma_f32_16x16x32_bf16(a0, bf[1][ks], acc[0][1], 0, 0, 0);
            acc[1][0] = __builtin_amdgcn_mfma_f32_16x16x32_bf16(a1, bf[0][ks], acc[1][0], 0, 0, 0);
            acc[1][1] = __builtin_amdgcn_mfma_f32_16x16x32_bf16(a1, bf[1][ks], acc[1][1], 0, 0, 0);
        }

        // ---- second silu + predicated colsum (D row = mt*16 + 4g + jj) ----
#pragma unroll
        for (int mt = 0; mt < 2; mt++)
#pragma unroll
            for (int nt = 0; nt < 2; nt++)
#pragma unroll
                for (int jj = 0; jj < 4; jj++) {
                    if (mt * 16 + g * 4 + jj < nloc)
                        msum[nt] += silu(acc[mt][nt][jj] + b2v[nt]);
                }
    }

    // cross-lane colsum: lanes l, l^16, l^32 share col (l&15); always write
    float v0 = msum[0]; v0 += __shfl_xor(v0, 16); v0 += __shfl_xor(v0, 32);
    float v1 = msum[1]; v1 += __shfl_xor(v1, 16); v1 += __shfl_xor(v1, 32);
    if (l < 16) {
        mp[w * 32 + l]      = v0;
        mp[w * 32 + 16 + l] = v1;
    }
}

// ------- node update + next-layer hi/hj via MFMA: 16 rows/block, 64 blocks -------
// m = m_part[0] + m_part[1], summed during A1 staging.
__global__ __launch_bounds__(256) void node_mfma(
    const float* __restrict__ h, const float* __restrict__ m0,
    const float* __restrict__ m1,
    const __bf16* __restrict__ w1nt, const float* __restrict__ b1n,
    const __bf16* __restrict__ w2nt, const float* __restrict__ b2n,
    float* __restrict__ hout, int do_hij,
    const __bf16* __restrict__ w1et, const float* __restrict__ b1e,
    const float* __restrict__ fold,
    float* __restrict__ hi, float* __restrict__ hj) {
    int r0 = blockIdx.x * 16;
    int t = threadIdx.x;
    int l = t & 63, w = t >> 6;
    int lr = l & 15, g = l >> 4;
    __shared__ __bf16 A1[16 * 256];
    __shared__ __bf16 A2[16 * Hc];
    __shared__ __bf16 A3[16 * Hc];
    __shared__ float hbuf[16 * Hc];

#pragma unroll
    for (int it = 0; it < 2; it++) {
        int idx = t + it * 256;
        int row = idx >> 5, blk = idx & 31, k0 = blk * 8;
        float4 v0, v1;
        if (k0 < 128) {
            const float* src = &h[(size_t)(r0 + row) * Hc + k0];
            v0 = *(const float4*)src; v1 = *(const float4*)(src + 4);
            *(float4*)&hbuf[row * Hc + k0] = v0;
            *(float4*)&hbuf[row * Hc + k0 + 4] = v1;
        } else {
            const float* s0 = &m0[(size_t)(r0 + row) * Hc + (k0 - 128)];
            const float* s1 = &m1[(size_t)(r0 + row) * Hc + (k0 - 128)];
            float4 a0 = *(const float4*)s0, a1 = *(const float4*)(s0 + 4);
            float4 c0v = *(const float4*)s1, c1 = *(const float4*)(s1 + 4);
            v0.x = a0.x + c0v.x; v0.y = a0.y + c0v.y;
            v0.z = a0.z + c0v.z; v0.w = a0.w + c0v.w;
            v1.x = a1.x + c1.x; v1.y = a1.y + c1.y;
            v1.z = a1.z + c1.z; v1.w = a1.w + c1.w;
        }
        bf16x8 o;
        o[0] = (__bf16)v0.x; o[1] = (__bf16)v0.y; o[2] = (__bf16)v0.z; o[3] = (__bf16)v0.w;
        o[4] = (__bf16)v1.x; o[5] = (__bf16)v1.y; o[6] = (__bf16)v1.z; o[7] = (__bf16)v1.w;
        *(bf16x8*)&A1[row * 256 + (blk ^ (row & 7)) * 8] = o;
    }
    int c0 = w * 32;
    bf16x8 b1f[2][8];
#pragma unroll
    for (int nt = 0; nt < 2; nt++)
#pragma unroll
        for (int ks = 0; ks < 8; ks++)
            b1f[nt][ks] = *(const bf16x8*)&w1nt[
                (size_t)(c0 + nt * 16 + lr) * 256 + ks * 32 + g * 8];
    __syncthreads();

    f32x4 acc[2] = {};
#pragma unroll
    for (int ks = 0; ks < 8; ks++) {
        bf16x8 a = *(const bf16x8*)&A1[lr * 256 + (((ks * 4 + g) ^ (lr & 7))) * 8];
        acc[0] = __builtin_amdgcn_mfma_f32_16x16x32_bf16(a, b1f[0][ks], acc[0], 0, 0, 0);
        acc[1] = __builtin_amdgcn_mfma_f32_16x16x32_bf16(a, b1f[1][ks], acc[1], 0, 0, 0);
    }
#pragma unroll
    for (int nt = 0; nt < 2; nt++) {
        int col = c0 + nt * 16 + lr;
        float bb = b1n[col];
#pragma unroll
        for (int j = 0; j < 4; j++) {
            int row = g * 4 + j;
            A2[row * Hc + ((col >> 3) ^ (row & 7)) * 8 + (col & 7)] =
                (__bf16)silu(acc[nt][j] + bb);
        }
    }
    __syncthreads();

    bf16x8 b2f[2][4];
#pragma unroll
    for (int nt = 0; nt < 2; nt++)
#pragma unroll
        for (int ks = 0; ks < 4; ks++)
            b2f[nt][ks] = *(const bf16x8*)&w2nt[
                (size_t)(c0 + nt * 16 + lr) * Hc + ks * 32 + g * 8];
    f32x4 acc2[2] = {};
#pragma unroll
    for (int ks = 0; ks < 4; ks++) {
        bf16x8 a = *(const bf16x8*)&A2[lr * Hc + (((ks * 4 + g) ^ (lr & 7))) * 8];
        acc2[0] = __builtin_amdgcn_mfma_f32_16x16x32_bf16(a, b2f[0][ks], acc2[0], 0, 0, 0);
        acc2[1] = __builtin_amdgcn_mfma_f32_16x16x32_bf16(a, b2f[1][ks], acc2[1], 0, 0, 0);
    }
#pragma unroll
    for (int nt = 0; nt < 2; nt++) {
        int col = c0 + nt * 16 + lr;
        float bb = b2n[col];
#pragma unroll
        for (int j = 0; j < 4; j++) {
            int row = g * 4 + j;
            float hnew = hbuf[row * Hc + col] + acc2[nt][j] + bb;
            hout[(size_t)(r0 + row) * Hc + col] = hnew;
            A3[row * Hc + ((col >> 3) ^ (row & 7)) * 8 + (col & 7)] = (__bf16)hnew;
        }
    }
    if (!do_hij) return;
    __syncthreads();

    int c3 = w * 64;
    bf16x8 b3[4][4];
#pragma unroll
    for (int nt = 0; nt < 4; nt++)
#pragma unroll
        for (int ks = 0; ks < 4; ks++)
            b3[nt][ks] = *(const bf16x8*)&w1et[
                (size_t)(c3 + nt * 16 + lr) * Hc + ks * 32 + g * 8];
    f32x4 acc3[4] = {};
#pragma unroll
    for (int ks = 0; ks < 4; ks++) {
        bf16x8 a = *(const bf16x8*)&A3[lr * Hc + (((ks * 4 + g) ^ (lr & 7))) * 8];
#pragma unroll
        for (int nt = 0; nt < 4; nt++)
            acc3[nt] = __builtin_amdgcn_mfma_f32_16x16x32_bf16(a, b3[nt][ks], acc3[nt], 0, 0, 0);
    }
#pragma unroll
    for (int nt = 0; nt < 4; nt++) {
        int col = c3 + nt * 16 + lr;
#pragma unroll
        for (int j = 0; j < 4; j++) {
            int row = g * 4 + j;
            if (col < 128)
                hi[(size_t)(r0 + row) * Hc + col] = acc3[nt][j] + b1e[col] + fold[col];
            else
                hj[(size_t)(r0 + row) * Hc + (col - 128)] = acc3[nt][j];
        }
    }
}

extern "C" void kernel_launch(void* const* d_in, const int* in_sizes, int n_in,
                              void* d_out, int out_size, void* d_ws, size_t ws_size,
                              hipStream_t stream) {
    const float* coords     = (const float*)d_in[0];
    const float* contacts   = (const float*)d_in[1];
    const float* node_feats = (const float*)d_in[2];
    const float* in_w       = (const float*)d_in[3];
    const float* in_b       = (const float*)d_in[4];
    const float* e_w1       = (const float*)d_in[5];   // 3 x 258 x 128
    const float* e_b1       = (const float*)d_in[6];
    const float* e_w2       = (const float*)d_in[7];   // 3 x 128 x 128
    const float* e_b2       = (const float*)d_in[8];
    const float* n_w1       = (const float*)d_in[9];   // 3 x 256 x 128
    const float* n_b1       = (const float*)d_in[10];
    const float* n_w2       = (const float*)d_in[11];  // 3 x 128 x 128
    const float* n_b2       = (const float*)d_in[12];

    float* ws = (float*)d_ws;
    float* h  = ws;                                    // 131072 floats
    float* hi = ws + 131072;
    float* hj = ws + 262144;
    unsigned short* elist = (unsigned short*)(ws + 524288);   // 262144 floats
    int*   ecnt = (int*)(ws + 786432);                        // 1024
    __bf16* in_wt = (__bf16*)(ws + 787456);                   // 4096 bf16
    __bf16* w1et  = (__bf16*)(ws + 789504);                   // 98304 bf16
    __bf16* w2te  = (__bf16*)(ws + 838656);                   // 49152 bf16
    __bf16* w1nt  = (__bf16*)(ws + 863232);                   // 98304 bf16
    __bf16* w2nt  = (__bf16*)(ws + 912384);                   // 49152 bf16
    float* m_part = ws + 936960;                              // 2*131072 floats
    float* m0 = m_part;
    float* m1 = m_part + 131072;

    prep_all<<<256 + 1168, 256, 0, stream>>>(
        contacts, elist, ecnt,
        in_w, e_w1, e_w2, n_w1, n_w2,
        in_wt, w1et, w2te, w1nt, w2nt);
    input_mfma<<<ROWS / 16, 256, 0, stream>>>(
        node_feats, in_wt, in_b,
        w1et, e_b1, e_w1 + (size_t)257 * Hc,
        h, hi, hj);

    for (int l = 0; l < 3; l++) {
        const float* w1 = e_w1 + (size_t)l * 258 * Hc;
        edge_kernel<<<ROWS * 2, 256, 0, stream>>>(hi, hj, coords, elist, ecnt,
                                                  w1 + 2 * Hc * Hc,
                                                  w2te + (size_t)l * Hc * Hc,
                                                  e_b2 + l * Hc, m_part);
        int do_hij = (l < 2);
        int lnext = (l + 1 < 3) ? l + 1 : 0;
        float* hout = (l == 2) ? (float*)d_out : h;
        node_mfma<<<ROWS / 16, 256, 0, stream>>>(
            h, m0, m1,
            w1nt + (size_t)l * 128 * 256, n_b1 + l * Hc,
            w2nt + (size_t)l * 128 * 128, n_b2 + l * Hc,
            hout, do_hij,
            w1et + (size_t)lnext * 256 * 128, e_b1 + lnext * Hc,
            e_w1 + (size_t)lnext * 258 * Hc + (size_t)257 * Hc,
            hi, hj);
    }
}

// Round 11
// 181.884 us; speedup vs baseline: 1.0615x; 1.0150x over previous
//
#include <hip/hip_runtime.h>
#include <hip/hip_bf16.h>

// SE3StructEncoder: sparse edge-MLP graph network. B=2, L=512, H=128, 3 layers.
// Round 11: dependency-chain reduction. prep_all deleted (was 2 serial stages);
// all kernels load/convert their weight fragments inline (8 stride-512B fp32
// loads per fragment, ILP-covered). Edge kernel ballot-compacts its own row's
// contacts into LDS (wave 0) overlapped with fragment loads (waves 1-3).
// Edge shape = round-7 best (1 block/row, ET=32 loop, inline dist, single m).
// 7 dispatches: input, (edge, node) x 3.

#define Hc 128
#define Lc 512
#define ROWS 1024     // B*L

typedef __bf16 bf16x8 __attribute__((ext_vector_type(8)));
typedef float  f32x4  __attribute__((ext_vector_type(4)));

__device__ __forceinline__ float silu(float x) {
    return x / (1.f + __expf(-x));
}

// frag of W^T: returns bf16 of W[k0+u][col], u=0..7 (W row-major [K][ldw])
__device__ __forceinline__ bf16x8 load_fragT(const float* __restrict__ W,
                                             int col, int k0, int ldw) {
    bf16x8 o;
#pragma unroll
    for (int u = 0; u < 8; u++) o[u] = (__bf16)W[(size_t)(k0 + u) * ldw + col];
    return o;
}

// ------- input proj + layer-0 hi/hj via MFMA: 16 rows/block, 64 blocks -------
__global__ __launch_bounds__(256) void input_mfma(
    const float* __restrict__ nf, const float* __restrict__ in_w,
    const float* __restrict__ in_b,
    const float* __restrict__ e_w1_0, const float* __restrict__ b1e,
    float* __restrict__ h, float* __restrict__ hi, float* __restrict__ hj) {
    int r0 = blockIdx.x * 16;
    int t = threadIdx.x;
    int l = t & 63, w = t >> 6;
    int lr = l & 15, g = l >> 4;
    __shared__ __bf16 A0[16 * 32];     // swizzled [row][k], blk ^ (row&3)
    __shared__ __bf16 A3[16 * Hc];     // swizzled [row][k], blk ^ (row&7)

    if (t < 64) {
        int row = t >> 2, blk = t & 3, k0 = blk * 8;
        const float* src = &nf[(size_t)(r0 + row) * 32 + k0];
        float4 v0 = *(const float4*)src, v1 = *(const float4*)(src + 4);
        bf16x8 o;
        o[0] = (__bf16)v0.x; o[1] = (__bf16)v0.y; o[2] = (__bf16)v0.z; o[3] = (__bf16)v0.w;
        o[4] = (__bf16)v1.x; o[5] = (__bf16)v1.y; o[6] = (__bf16)v1.z; o[7] = (__bf16)v1.w;
        *(bf16x8*)&A0[row * 32 + (blk ^ (row & 3)) * 8] = o;
    }
    int c0 = w * 32;
    bf16x8 bf0[2];
#pragma unroll
    for (int nt = 0; nt < 2; nt++)
        bf0[nt] = load_fragT(in_w, c0 + nt * 16 + lr, g * 8, Hc);
    __syncthreads();
    f32x4 acc[2] = {};
    {
        bf16x8 a = *(const bf16x8*)&A0[lr * 32 + (g ^ (lr & 3)) * 8];
        acc[0] = __builtin_amdgcn_mfma_f32_16x16x32_bf16(a, bf0[0], acc[0], 0, 0, 0);
        acc[1] = __builtin_amdgcn_mfma_f32_16x16x32_bf16(a, bf0[1], acc[1], 0, 0, 0);
    }
#pragma unroll
    for (int nt = 0; nt < 2; nt++) {
        int col = c0 + nt * 16 + lr;
        float bb = in_b[col];
#pragma unroll
        for (int j = 0; j < 4; j++) {
            int row = g * 4 + j;
            float hv = acc[nt][j] + bb;
            h[(size_t)(r0 + row) * Hc + col] = hv;
            A3[row * Hc + ((col >> 3) ^ (row & 7)) * 8 + (col & 7)] = (__bf16)hv;
        }
    }
    __syncthreads();
    // hi/hj = A3 @ w1e0^T  (cols 0..127 -> hi with b1e+fold, 128..255 -> hj)
    int c3 = w * 64;
    bf16x8 b3[4][4];
#pragma unroll
    for (int nt = 0; nt < 4; nt++) {
        int col = c3 + nt * 16 + lr;
        const float* Wb = (col < 128) ? (e_w1_0 + col)
                                      : (e_w1_0 + 128 * Hc + (col - 128));
#pragma unroll
        for (int ks = 0; ks < 4; ks++) {
            int k0 = ks * 32 + g * 8;
            bf16x8 o;
#pragma unroll
            for (int u = 0; u < 8; u++) o[u] = (__bf16)Wb[(size_t)(k0 + u) * Hc];
            b3[nt][ks] = o;
        }
    }
    const float* fold = e_w1_0 + (size_t)257 * Hc;
    f32x4 acc3[4] = {};
#pragma unroll
    for (int ks = 0; ks < 4; ks++) {
        bf16x8 a = *(const bf16x8*)&A3[lr * Hc + (((ks * 4 + g) ^ (lr & 7))) * 8];
#pragma unroll
        for (int nt = 0; nt < 4; nt++)
            acc3[nt] = __builtin_amdgcn_mfma_f32_16x16x32_bf16(a, b3[nt][ks], acc3[nt], 0, 0, 0);
    }
#pragma unroll
    for (int nt = 0; nt < 4; nt++) {
        int col = c3 + nt * 16 + lr;
#pragma unroll
        for (int j = 0; j < 4; j++) {
            int row = g * 4 + j;
            if (col < 128)
                hi[(size_t)(r0 + row) * Hc + col] = acc3[nt][j] + b1e[col] + fold[col];
            else
                hj[(size_t)(r0 + row) * Hc + (col - 128)] = acc3[nt][j];
        }
    }
}

// ---------------- edge kernel: per (b,i) row, self-built edge list ----------------
// m_i = sum_{j in edges(i)} silu( silu(pre_ij) @ w2 + b2 )
// pre_ij = hi'[i] + hj[j] + dist(i,j)*w1d  (b1 + contact fold already in hi')
// wave 0 ballot-compacts contacts row -> jlist (LDS) while waves 1-3 load
// their w2 fragments inline from fp32 e_w2 (stride-512B gathers, ILP).
__global__ __launch_bounds__(256) void edge_kernel(
    const float* __restrict__ hi, const float* __restrict__ hj,
    const float* __restrict__ coords, const float* __restrict__ contacts,
    const float* __restrict__ w1d, const float* __restrict__ e_w2_l,
    const float* __restrict__ b2, float* __restrict__ m_out) {
    int r = blockIdx.x;
    int b = r >> 9;
    int i = r & (Lc - 1);
    int t = threadIdx.x;
    int l = t & 63, w = t >> 6;
    int lr = l & 15, g = l >> 4;

    __shared__ __bf16 S[32 * Hc];          // 8 KB, swizzled [edge][c]
    __shared__ unsigned short jlist[Lc];   // 1 KB
    __shared__ int cnt_s;

    // wave 0: build this row's edge list
    if (t < 64) {
        const float* crow = contacts + (size_t)r * Lc;
        int c = 0;
        for (int seg = 0; seg < Lc; seg += 64) {
            float v = crow[seg + t];
            unsigned long long mask = __ballot(v > 0.f);
            if (v > 0.f) {
                int pos = c + __popcll(mask & ((1ull << t) - 1ull));
                jlist[pos] = (unsigned short)(seg + t);
            }
            c += __popcll(mask);
        }
        if (t == 0) cnt_s = c;
    }

    // all waves: B fragments (wave w owns cols w*32..+31), inline from fp32
    bf16x8 bf[2][4];
#pragma unroll
    for (int nt = 0; nt < 2; nt++)
#pragma unroll
        for (int kk = 0; kk < 4; kk++)
            bf[nt][kk] = load_fragT(e_w2_l, w * 32 + nt * 16 + lr, kk * 32 + g * 8, Hc);
    float b2v[2] = { b2[w * 32 + lr], b2[w * 32 + 16 + lr] };
    float msum[2] = { 0.f, 0.f };

    // fill-role constants: thread -> (edge e_f=t>>3, 16-col slice c0)
    int e_f = t >> 3;
    int cg  = t & 7;
    int c0  = cg * 16;
    float cxi = coords[(b * Lc + i) * 3 + 0];
    float cyi = coords[(b * Lc + i) * 3 + 1];
    float czi = coords[(b * Lc + i) * 3 + 2];
    float4 hi4[4], wd4[4];
#pragma unroll
    for (int q = 0; q < 4; q++) {
        hi4[q] = *(const float4*)&hi[(size_t)r * Hc + c0 + q * 4];
        wd4[q] = *(const float4*)&w1d[c0 + q * 4];
    }
    const float* hjb = hj + (size_t)(b * Lc) * Hc;

    __syncthreads();
    int cnt = cnt_s;

    for (int base = 0; base < cnt; base += 32) {
        if (base) __syncthreads();
        int nloc = cnt - base; if (nloc > 32) nloc = 32;
        // ---- fill S ----
        bf16x8 o0, o1;
        if (e_f < nloc) {
            int j = jlist[base + e_f];
            float dx = cxi - coords[(b * Lc + j) * 3 + 0];
            float dy = cyi - coords[(b * Lc + j) * 3 + 1];
            float dz = czi - coords[(b * Lc + j) * 3 + 2];
            float d = sqrtf(dx * dx + dy * dy + dz * dz);
            const float* hjrow = hjb + (size_t)j * Hc + c0;
            float v[16];
#pragma unroll
            for (int q = 0; q < 4; q++) {
                float4 hjv = *(const float4*)&hjrow[q * 4];
                v[q * 4 + 0] = silu(hi4[q].x + hjv.x + d * wd4[q].x);
                v[q * 4 + 1] = silu(hi4[q].y + hjv.y + d * wd4[q].y);
                v[q * 4 + 2] = silu(hi4[q].z + hjv.z + d * wd4[q].z);
                v[q * 4 + 3] = silu(hi4[q].w + hjv.w + d * wd4[q].w);
            }
#pragma unroll
            for (int u = 0; u < 8; u++) {
                o0[u] = (__bf16)v[u];
                o1[u] = (__bf16)v[8 + u];
            }
        } else {
#pragma unroll
            for (int u = 0; u < 8; u++) { o0[u] = (__bf16)0.f; o1[u] = (__bf16)0.f; }
        }
        int sw = e_f & 7;
        *(bf16x8*)&S[e_f * Hc + ((cg * 2) ^ sw) * 8]     = o0;
        *(bf16x8*)&S[e_f * Hc + ((cg * 2 + 1) ^ sw) * 8] = o1;
        __syncthreads();

        // ---- MFMA: D[e][col] = S @ w2, 2 M-tiles x 2 N-tiles x 4 K-steps ----
        f32x4 acc[2][2] = {};
#pragma unroll
        for (int ks = 0; ks < 4; ks++) {
            bf16x8 a0 = *(const bf16x8*)&S[lr * Hc + ((ks * 4 + g) ^ (lr & 7)) * 8];
            bf16x8 a1 = *(const bf16x8*)&S[(16 + lr) * Hc + ((ks * 4 + g) ^ (lr & 7)) * 8];
            acc[0][0] = __builtin_amdgcn_mfma_f32_16x16x32_bf16(a0, bf[0][ks], acc[0][0], 0, 0, 0);
            acc[0][1] = __builtin_amdgcn_mfma_f32_16x16x32_bf16(a0, bf[1][ks], acc[0][1], 0, 0, 0);
            acc[1][0] = __builtin_amdgcn_mfma_f32_16x16x32_bf16(a1, bf[0][ks], acc[1][0], 0, 0, 0);
            acc[1][1] = __builtin_amdgcn_mfma_f32_16x16x32_bf16(a1, bf[1][ks], acc[1][1], 0, 0, 0);
        }

        // ---- second silu + predicated colsum (D row = mt*16 + 4g + jj) ----
#pragma unroll
        for (int mt = 0; mt < 2; mt++)
#pragma unroll
            for (int nt = 0; nt < 2; nt++)
#pragma unroll
                for (int jj = 0; jj < 4; jj++) {
                    if (mt * 16 + g * 4 + jj < nloc)
                        msum[nt] += silu(acc[mt][nt][jj] + b2v[nt]);
                }
    }

    // cross-lane colsum: lanes l, l^16, l^32 share col (l&15); always write
    float v0 = msum[0]; v0 += __shfl_xor(v0, 16); v0 += __shfl_xor(v0, 32);
    float v1 = msum[1]; v1 += __shfl_xor(v1, 16); v1 += __shfl_xor(v1, 32);
    if (l < 16) {
        m_out[(size_t)r * Hc + w * 32 + l]      = v0;
        m_out[(size_t)r * Hc + w * 32 + 16 + l] = v1;
    }
}

// ------- node update + next-layer hi/hj via MFMA: 16 rows/block, 64 blocks -------
// h' = h + silu([h||m]@w1n + b1n)@w2n + b2n ; hi/hj = h'@w1e (+b1e+fold)
__global__ __launch_bounds__(256) void node_mfma(
    const float* __restrict__ h, const float* __restrict__ m,
    const float* __restrict__ n_w1_l, const float* __restrict__ b1n,
    const float* __restrict__ n_w2_l, const float* __restrict__ b2n,
    float* __restrict__ hout, int do_hij,
    const float* __restrict__ e_w1_n, const float* __restrict__ b1e,
    float* __restrict__ hi, float* __restrict__ hj) {
    int r0 = blockIdx.x * 16;
    int t = threadIdx.x;
    int l = t & 63, w = t >> 6;
    int lr = l & 15, g = l >> 4;
    __shared__ __bf16 A1[16 * 256];
    __shared__ __bf16 A2[16 * Hc];
    __shared__ __bf16 A3[16 * Hc];
    __shared__ float hbuf[16 * Hc];

#pragma unroll
    for (int it = 0; it < 2; it++) {
        int idx = t + it * 256;
        int row = idx >> 5, blk = idx & 31, k0 = blk * 8;
        const float* src = (k0 < 128)
            ? &h[(size_t)(r0 + row) * Hc + k0]
            : &m[(size_t)(r0 + row) * Hc + (k0 - 128)];
        float4 v0 = *(const float4*)src, v1 = *(const float4*)(src + 4);
        bf16x8 o;
        o[0] = (__bf16)v0.x; o[1] = (__bf16)v0.y; o[2] = (__bf16)v0.z; o[3] = (__bf16)v0.w;
        o[4] = (__bf16)v1.x; o[5] = (__bf16)v1.y; o[6] = (__bf16)v1.z; o[7] = (__bf16)v1.w;
        *(bf16x8*)&A1[row * 256 + (blk ^ (row & 7)) * 8] = o;
        if (k0 < 128) {
            *(float4*)&hbuf[row * Hc + k0] = v0;
            *(float4*)&hbuf[row * Hc + k0 + 4] = v1;
        }
    }
    int c0 = w * 32;
    bf16x8 b1f[2][8];
#pragma unroll
    for (int nt = 0; nt < 2; nt++)
#pragma unroll
        for (int ks = 0; ks < 8; ks++)
            b1f[nt][ks] = load_fragT(n_w1_l, c0 + nt * 16 + lr, ks * 32 + g * 8, Hc);
    __syncthreads();

    f32x4 acc[2] = {};
#pragma unroll
    for (int ks = 0; ks < 8; ks++) {
        bf16x8 a = *(const bf16x8*)&A1[lr * 256 + (((ks * 4 + g) ^ (lr & 7))) * 8];
        acc[0] = __builtin_amdgcn_mfma_f32_16x16x32_bf16(a, b1f[0][ks], acc[0], 0, 0, 0);
        acc[1] = __builtin_amdgcn_mfma_f32_16x16x32_bf16(a, b1f[1][ks], acc[1], 0, 0, 0);
    }
#pragma unroll
    for (int nt = 0; nt < 2; nt++) {
        int col = c0 + nt * 16 + lr;
        float bb = b1n[col];
#pragma unroll
        for (int j = 0; j < 4; j++) {
            int row = g * 4 + j;
            A2[row * Hc + ((col >> 3) ^ (row & 7)) * 8 + (col & 7)] =
                (__bf16)silu(acc[nt][j] + bb);
        }
    }
    __syncthreads();

    bf16x8 b2f[2][4];
#pragma unroll
    for (int nt = 0; nt < 2; nt++)
#pragma unroll
        for (int ks = 0; ks < 4; ks++)
            b2f[nt][ks] = load_fragT(n_w2_l, c0 + nt * 16 + lr, ks * 32 + g * 8, Hc);
    f32x4 acc2[2] = {};
#pragma unroll
    for (int ks = 0; ks < 4; ks++) {
        bf16x8 a = *(const bf16x8*)&A2[lr * Hc + (((ks * 4 + g) ^ (lr & 7))) * 8];
        acc2[0] = __builtin_amdgcn_mfma_f32_16x16x32_bf16(a, b2f[0][ks], acc2[0], 0, 0, 0);
        acc2[1] = __builtin_amdgcn_mfma_f32_16x16x32_bf16(a, b2f[1][ks], acc2[1], 0, 0, 0);
    }
#pragma unroll
    for (int nt = 0; nt < 2; nt++) {
        int col = c0 + nt * 16 + lr;
        float bb = b2n[col];
#pragma unroll
        for (int j = 0; j < 4; j++) {
            int row = g * 4 + j;
            float hnew = hbuf[row * Hc + col] + acc2[nt][j] + bb;
            hout[(size_t)(r0 + row) * Hc + col] = hnew;
            A3[row * Hc + ((col >> 3) ^ (row & 7)) * 8 + (col & 7)] = (__bf16)hnew;
        }
    }
    if (!do_hij) return;
    __syncthreads();

    int c3 = w * 64;
    bf16x8 b3[4][4];
#pragma unroll
    for (int nt = 0; nt < 4; nt++) {
        int col = c3 + nt * 16 + lr;
        const float* Wb = (col < 128) ? (e_w1_n + col)
                                      : (e_w1_n + 128 * Hc + (col - 128));
#pragma unroll
        for (int ks = 0; ks < 4; ks++) {
            int k0 = ks * 32 + g * 8;
            bf16x8 o;
#pragma unroll
            for (int u = 0; u < 8; u++) o[u] = (__bf16)Wb[(size_t)(k0 + u) * Hc];
            b3[nt][ks] = o;
        }
    }
    const float* fold = e_w1_n + (size_t)257 * Hc;
    f32x4 acc3[4] = {};
#pragma unroll
    for (int ks = 0; ks < 4; ks++) {
        bf16x8 a = *(const bf16x8*)&A3[lr * Hc + (((ks * 4 + g) ^ (lr & 7))) * 8];
#pragma unroll
        for (int nt = 0; nt < 4; nt++)
            acc3[nt] = __builtin_amdgcn_mfma_f32_16x16x32_bf16(a, b3[nt][ks], acc3[nt], 0, 0, 0);
    }
#pragma unroll
    for (int nt = 0; nt < 4; nt++) {
        int col = c3 + nt * 16 + lr;
#pragma unroll
        for (int j = 0; j < 4; j++) {
            int row = g * 4 + j;
            if (col < 128)
                hi[(size_t)(r0 + row) * Hc + col] = acc3[nt][j] + b1e[col] + fold[col];
            else
                hj[(size_t)(r0 + row) * Hc + (col - 128)] = acc3[nt][j];
        }
    }
}

extern "C" void kernel_launch(void* const* d_in, const int* in_sizes, int n_in,
                              void* d_out, int out_size, void* d_ws, size_t ws_size,
                              hipStream_t stream) {
    const float* coords     = (const float*)d_in[0];
    const float* contacts   = (const float*)d_in[1];
    const float* node_feats = (const float*)d_in[2];
    const float* in_w       = (const float*)d_in[3];
    const float* in_b       = (const float*)d_in[4];
    const float* e_w1       = (const float*)d_in[5];   // 3 x 258 x 128
    const float* e_b1       = (const float*)d_in[6];
    const float* e_w2       = (const float*)d_in[7];   // 3 x 128 x 128
    const float* e_b2       = (const float*)d_in[8];
    const float* n_w1       = (const float*)d_in[9];   // 3 x 256 x 128
    const float* n_b1       = (const float*)d_in[10];
    const float* n_w2       = (const float*)d_in[11];  // 3 x 128 x 128
    const float* n_b2       = (const float*)d_in[12];

    float* ws = (float*)d_ws;
    float* h  = ws;                  // 131072 floats
    float* hi = ws + 131072;
    float* hj = ws + 262144;
    float* m  = ws + 393216;

    input_mfma<<<ROWS / 16, 256, 0, stream>>>(
        node_feats, in_w, in_b, e_w1, e_b1, h, hi, hj);

    for (int l = 0; l < 3; l++) {
        const float* w1 = e_w1 + (size_t)l * 258 * Hc;
        edge_kernel<<<ROWS, 256, 0, stream>>>(
            hi, hj, coords, contacts,
            w1 + 2 * Hc * Hc,                 // w1d row 256
            e_w2 + (size_t)l * Hc * Hc,
            e_b2 + l * Hc, m);
        int do_hij = (l < 2);
        int lnext = (l + 1 < 3) ? l + 1 : 0;
        float* hout = (l == 2) ? (float*)d_out : h;
        node_mfma<<<ROWS / 16, 256, 0, stream>>>(
            h, m,
            n_w1 + (size_t)l * 256 * Hc, n_b1 + l * Hc,
            n_w2 + (size_t)l * Hc * Hc,  n_b2 + l * Hc,
            hout, do_hij,
            e_w1 + (size_t)lnext * 258 * Hc, e_b1 + lnext * Hc,
            hi, hj);
    }
}